// Round 2
// baseline (687.724 us; speedup 1.0000x reference)
//
#include <hip/hip_runtime.h>

typedef _Float16 half_t;
typedef __attribute__((ext_vector_type(8))) _Float16 half8;
typedef __attribute__((ext_vector_type(4))) _Float16 half4;
typedef __attribute__((ext_vector_type(4))) float f32x4;

#define B_ 4
#define N_ 4096
#define D_ 1024
#define R_ (B_ * N_) // 16384

// ---------------------------------------------------------------------------
// async global->LDS, 16B per lane. LDS dest must be wave-uniform base + lane*16.
__device__ __forceinline__ void gload_lds16(const half_t* g, half_t* l) {
    __builtin_amdgcn_global_load_lds(
        (const __attribute__((address_space(1))) unsigned int*)g,
        (__attribute__((address_space(3))) unsigned int*)l, 16, 0, 0);
}

// ---------------------------------------------------------------------------
// C[m,n] = sum_k A[m,k] * Bt[n,k]   (A row-major [M,K], B given transposed [N,K])
// 128x128 tile, BK=32, 256 threads (4 waves, each 64x64 = 4x4 MFMA 16x16x32).
// LDS is in FRAGMENT order: block b (16 rows) x lane x 8 halfs, so each wave's
// fragment read is ds_read_b128 at base + lane*16 -> sequential, conflict-free.
// EPI: 0 = fp32 C, 1 = f16 C, 2 = fp32 C + bias (bias indexed by column)
// ZSHIFT: blockIdx.z = (batch << ZSHIFT) | ksplit; k window = ksplit*K .. +K.
//         C offset uses full blockIdx.z (partials laid out per z).
template <int EPI, int ZSHIFT>
__global__ __launch_bounds__(256) void gemm_bt(
    const half_t* __restrict__ A, const half_t* __restrict__ Bt,
    void* __restrict__ Cv, const float* __restrict__ bias,
    int lda, int ldb, int ldc, int K,
    long sA, long sB, long sC, float scale)
{
    __shared__ __align__(16) half_t As[128 * 32];
    __shared__ __align__(16) half_t Bs[128 * 32];

    const int t = threadIdx.x;
    const int wave = t >> 6;
    const int lane = t & 63;
    const int l15 = lane & 15;
    const int q = lane >> 4;
    const int m0 = blockIdx.y * 128;
    const int n0 = blockIdx.x * 128;
    const long zb = blockIdx.z >> ZSHIFT;
    const int zs = blockIdx.z & ((1 << ZSHIFT) - 1);

    // fragment-order staging map: thread t -> (block = t>>6, lane slot = t&63)
    // slot lane (q*16+l15) of block b holds A[16b + l15][kchunk q]
    const int fr = ((t >> 6) << 4) + (t & 15); // row in [0,64)
    const int fc = ((t >> 4) & 3) * 8;         // k offset in halfs

    const half_t* a0 = A + zb * sA + (long)(m0 + fr) * lda + (long)zs * K + fc;
    const half_t* a1 = a0 + 64 * (long)lda;
    const half_t* b0 = Bt + zb * sB + (long)(n0 + fr) * ldb + (long)zs * K + fc;
    const half_t* b1 = b0 + 64 * (long)ldb;

    f32x4 acc[4][4] = {};

    const int wr = (wave >> 1) * 64;
    const int wc = (wave & 1) * 64;
    // fragment read bases (halfs): block index * 512
    const int abase = (wave >> 1) * 2048 + lane * 8;
    const int bbase = (wave & 1) * 2048 + lane * 8;

    for (int k0 = 0; k0 < K; k0 += 32) {
        gload_lds16(a0 + k0, As + t * 8);
        gload_lds16(a1 + k0, As + (t + 256) * 8);
        gload_lds16(b0 + k0, Bs + t * 8);
        gload_lds16(b1 + k0, Bs + (t + 256) * 8);
        __syncthreads();

        half8 af[4], bfr[4];
#pragma unroll
        for (int i = 0; i < 4; i++)
            af[i] = *(const half8*)(As + abase + i * 512);
#pragma unroll
        for (int j = 0; j < 4; j++)
            bfr[j] = *(const half8*)(Bs + bbase + j * 512);
#pragma unroll
        for (int i = 0; i < 4; i++)
#pragma unroll
            for (int j = 0; j < 4; j++)
                acc[i][j] = __builtin_amdgcn_mfma_f32_16x16x32_f16(af[i], bfr[j], acc[i][j], 0, 0, 0);
        __syncthreads();
    }

    if (EPI == 1) {
        half_t* C = (half_t*)Cv + (long)blockIdx.z * sC + (long)m0 * ldc + n0;
#pragma unroll
        for (int i = 0; i < 4; i++)
#pragma unroll
            for (int j = 0; j < 4; j++) {
                const int col = wc + j * 16 + l15;
#pragma unroll
                for (int r = 0; r < 4; r++) {
                    const int row = wr + i * 16 + q * 4 + r;
                    C[(long)row * ldc + col] = (half_t)(acc[i][j][r] * scale);
                }
            }
    } else {
        float* C = (float*)Cv + (long)blockIdx.z * sC + (long)m0 * ldc + n0;
#pragma unroll
        for (int i = 0; i < 4; i++)
#pragma unroll
            for (int j = 0; j < 4; j++) {
                const int col = wc + j * 16 + l15;
                const float bv = (EPI == 2) ? bias[n0 + col] : 0.0f;
#pragma unroll
                for (int r = 0; r < 4; r++) {
                    const int row = wr + i * 16 + q * 4 + r;
                    C[(long)row * ldc + col] = acc[i][j][r] * scale + bv;
                }
            }
    }
}

// ---------------------------------------------------------------------------
// sum 4 split-K fp32 partials -> f16. P laid [z = b*4+s][1M floats].
__global__ __launch_bounds__(256) void ctx_reduce(
    const float* __restrict__ P, half_t* __restrict__ ctx)
{
    const long i = ((long)blockIdx.x * 256 + threadIdx.x) * 4;
    const long b = i >> 20;
    const long idx = i & ((1L << 20) - 1);
    const float* p = P + (b * 4) * (1L << 20) + idx;
    const float4 s0 = *(const float4*)(p);
    const float4 s1 = *(const float4*)(p + (1L << 20));
    const float4 s2 = *(const float4*)(p + 2 * (1L << 20));
    const float4 s3 = *(const float4*)(p + 3 * (1L << 20));
    half4 o = {(half_t)(s0.x + s1.x + s2.x + s3.x),
               (half_t)(s0.y + s1.y + s2.y + s3.y),
               (half_t)(s0.z + s1.z + s2.z + s3.z),
               (half_t)(s0.w + s1.w + s2.w + s3.w)};
    *(half4*)(ctx + i) = o;
}

// ---------------------------------------------------------------------------
// fp32 -> f16 elementwise (8 elems/thread)
__global__ __launch_bounds__(256) void convert_f32_f16(
    const float* __restrict__ in, half_t* __restrict__ out)
{
    const long i = ((long)blockIdx.x * 256 + threadIdx.x) * 8;
    const float4 a = *(const float4*)(in + i);
    const float4 b = *(const float4*)(in + i + 4);
    half8 o = {(half_t)a.x, (half_t)a.y, (half_t)a.z, (half_t)a.w,
               (half_t)b.x, (half_t)b.y, (half_t)b.z, (half_t)b.w};
    *(half8*)(out + i) = o;
}

// ---------------------------------------------------------------------------
// 1024x1024 fp32 -> f16 transposed (Wt[j][i] = W[i][j]); block (32,8)
__global__ void transpose_w(const float* __restrict__ W, half_t* __restrict__ Wt)
{
    __shared__ float tile[32][33];
    const int tx = threadIdx.x, ty = threadIdx.y;
    const int bx = blockIdx.x * 32, by = blockIdx.y * 32;
#pragma unroll
    for (int yy = ty; yy < 32; yy += 8)
        tile[yy][tx] = W[(long)(by + yy) * 1024 + bx + tx];
    __syncthreads();
#pragma unroll
    for (int yy = ty; yy < 32; yy += 8)
        Wt[(long)(bx + yy) * 1024 + by + tx] = (half_t)tile[tx][yy];
}

// ---------------------------------------------------------------------------
// row softmax over 1024 features; one block per row. Output scaled by 64 (f16
// subnormal guard; compensated in final epilogue scale).
__global__ __launch_bounds__(256) void softmax_rows(
    const float* __restrict__ L, half_t* __restrict__ Qh)
{
    const int r = blockIdx.x;
    const int t = threadIdx.x;
    const float4 x = ((const float4*)(L + (long)r * 1024))[t];
    float m = fmaxf(fmaxf(x.x, x.y), fmaxf(x.z, x.w));
#pragma unroll
    for (int o = 32; o > 0; o >>= 1) m = fmaxf(m, __shfl_xor(m, o, 64));
    __shared__ float redm[4], reds[4];
    const int wave = t >> 6;
    if ((t & 63) == 0) redm[wave] = m;
    __syncthreads();
    m = fmaxf(fmaxf(redm[0], redm[1]), fmaxf(redm[2], redm[3]));
    const float e0 = __expf(x.x - m), e1 = __expf(x.y - m),
                e2 = __expf(x.z - m), e3 = __expf(x.w - m);
    float s = e0 + e1 + e2 + e3;
#pragma unroll
    for (int o = 32; o > 0; o >>= 1) s += __shfl_xor(s, o, 64);
    if ((t & 63) == 0) reds[wave] = s;
    __syncthreads();
    s = reds[0] + reds[1] + reds[2] + reds[3];
    const float rs = 64.0f / s;
    half4 o4 = {(half_t)(e0 * rs), (half_t)(e1 * rs),
                (half_t)(e2 * rs), (half_t)(e3 * rs)};
    ((half4*)(Qh + (long)r * 1024))[t] = o4;
}

// ---------------------------------------------------------------------------
// column softmax stats over N per (b,d): partial online max/sum per 256-row chunk
__global__ __launch_bounds__(256) void colstat1(
    const float* __restrict__ L, float* __restrict__ pm, float* __restrict__ ps)
{
    const int t = threadIdx.x;
    const int d = blockIdx.x * 256 + t;
    const int nc = blockIdx.y, b = blockIdx.z;
    const float* p = L + ((long)(b * N_ + nc * 256)) * 1024 + d;
    float m = -1e30f, s = 0.0f;
    for (int i = 0; i < 256; i++) {
        const float x = p[(long)i * 1024];
        const float nm = fmaxf(m, x);
        s = s * __expf(m - nm) + __expf(x - nm);
        m = nm;
    }
    const int o = (b * 16 + nc) * 1024 + d;
    pm[o] = m;
    ps[o] = s;
}

__global__ __launch_bounds__(256) void colstat2(
    const float* __restrict__ pm, const float* __restrict__ ps,
    float* __restrict__ cmax, float* __restrict__ crcp)
{
    const int c = blockIdx.x * 256 + threadIdx.x; // [0, 4096)
    const int b = c >> 10, d = c & 1023;
    float m = -1e30f;
#pragma unroll
    for (int j = 0; j < 16; j++) m = fmaxf(m, pm[(b * 16 + j) * 1024 + d]);
    float s = 0.0f;
#pragma unroll
    for (int j = 0; j < 16; j++)
        s += ps[(b * 16 + j) * 1024 + d] * __expf(pm[(b * 16 + j) * 1024 + d] - m);
    cmax[c] = m;
    crcp[c] = 1.0f / s;
}

// ---------------------------------------------------------------------------
// [B,N,D] fp32 -> [B,D,N] f16, optionally applying column softmax (exp/Z * 64)
template <bool SM>
__global__ __launch_bounds__(256) void transpose_nd(
    const float* __restrict__ L, half_t* __restrict__ Out,
    const float* __restrict__ cmax, const float* __restrict__ crcp)
{
    __shared__ half_t tile[64][66]; // 66: odd word stride -> conflict-free
    const int t = threadIdx.x;
    const int n0 = blockIdx.x * 64, d0 = blockIdx.y * 64;
    const int b = blockIdx.z;
    const float* src = L + ((long)(b * N_ + n0)) * 1024 + d0;
#pragma unroll
    for (int i = 0; i < 16; i++) {
        const int idx = i * 256 + t;
        const int nl = idx >> 6, dl = idx & 63;
        float x = src[(long)nl * 1024 + dl];
        if (SM)
            x = __expf(x - cmax[b * 1024 + d0 + dl]) * (64.0f * crcp[b * 1024 + d0 + dl]);
        tile[dl][nl] = (half_t)x;
    }
    __syncthreads();
    half_t* dst = Out + ((long)(b * 1024 + d0)) * (long)N_ + n0;
#pragma unroll
    for (int i = 0; i < 16; i++) {
        const int idx = i * 256 + t;
        const int dl = idx >> 6, nl = idx & 63;
        dst[(long)dl * N_ + nl] = tile[dl][nl];
    }
}

// ---------------------------------------------------------------------------
extern "C" void kernel_launch(void* const* d_in, const int* in_sizes, int n_in,
                              void* d_out, int out_size, void* d_ws, size_t ws_size,
                              hipStream_t stream)
{
    const float* x  = (const float*)d_in[0];
    const float* Wq = (const float*)d_in[1];
    const float* Wk = (const float*)d_in[2];
    const float* Wv = (const float*)d_in[3];
    const float* Wo = (const float*)d_in[4];
    const float* bo = (const float*)d_in[5];
    float* out = (float*)d_out;

    char* w = (char*)d_ws;
    half_t* Xh  = (half_t*)w; w += (size_t)R_ * D_ * 2;       // 32 MiB
    float*  L   = (float*)w;  w += (size_t)R_ * D_ * 4;       // 64 MiB (Q/K/V logits, then ctx split-K partials)
    half_t* Qh  = (half_t*)w; w += (size_t)R_ * D_ * 2;       // 32 MiB (q * 64)
    half_t* Kt  = (half_t*)w; w += (size_t)R_ * D_ * 2;       // 32 MiB [B,D,N] (k * 64)
    half_t* Vt  = (half_t*)w; w += (size_t)R_ * D_ * 2;       // 32 MiB [B,D,N]
    half_t* Wt  = (half_t*)w; w += (size_t)D_ * D_ * 2;       // 2 MiB (reused)
    half_t* ctx = (half_t*)w; w += (size_t)B_ * D_ * D_ * 2;  // 8 MiB (64 * K^T V)
    half_t* Mt  = (half_t*)w; w += (size_t)B_ * D_ * D_ * 2;  // 8 MiB (64 * (ctx Wo)^T)
    float*  pm  = (float*)w;  w += (size_t)B_ * 16 * D_ * 4;
    float*  ps  = (float*)w;  w += (size_t)B_ * 16 * D_ * 4;
    float*  cmx = (float*)w;  w += (size_t)B_ * D_ * 4;
    float*  crp = (float*)w;  w += (size_t)B_ * D_ * 4;
    (void)ws_size; (void)in_sizes; (void)n_in; (void)out_size;

    const dim3 blk(256);
    const dim3 twb(32, 8), twg(32, 32);

    convert_f32_f16<<<R_ * D_ / (256 * 8), blk, 0, stream>>>(x, Xh);

    // ---- Q path
    transpose_w<<<twg, twb, 0, stream>>>(Wq, Wt);
    gemm_bt<0, 0><<<dim3(8, 128, 1), blk, 0, stream>>>(Xh, Wt, L, nullptr,
        1024, 1024, 1024, 1024, 0, 0, 0, 1.0f);
    softmax_rows<<<R_, blk, 0, stream>>>(L, Qh);

    // ---- K path (column softmax over sequence, then transpose to [B,D,N])
    transpose_w<<<twg, twb, 0, stream>>>(Wk, Wt);
    gemm_bt<0, 0><<<dim3(8, 128, 1), blk, 0, stream>>>(Xh, Wt, L, nullptr,
        1024, 1024, 1024, 1024, 0, 0, 0, 1.0f);
    colstat1<<<dim3(4, 16, B_), blk, 0, stream>>>(L, pm, ps);
    colstat2<<<16, blk, 0, stream>>>(pm, ps, cmx, crp);
    transpose_nd<true><<<dim3(64, 16, B_), blk, 0, stream>>>(L, Kt, cmx, crp);

    // ---- V path (transpose to [B,D,N])
    transpose_w<<<twg, twb, 0, stream>>>(Wv, Wt);
    gemm_bt<0, 0><<<dim3(8, 128, 1), blk, 0, stream>>>(Xh, Wt, L, nullptr,
        1024, 1024, 1024, 1024, 0, 0, 0, 1.0f);
    transpose_nd<false><<<dim3(64, 16, B_), blk, 0, stream>>>(L, Vt, nullptr, nullptr);

    // ---- ctx[b][d][e] = sum_n (64 k[n,d]) v[n,e], split-K=4 (z = b*4+s)
    // partials into L (exactly 64 MiB = 16 z-slices * 4 MiB)
    gemm_bt<0, 2><<<dim3(8, 8, 16), blk, 0, stream>>>(Kt, Vt, L, nullptr,
        N_, N_, 1024, N_ / 4,
        (long)D_ * N_, (long)D_ * N_, 1L << 20, 1.0f);
    ctx_reduce<<<4096, blk, 0, stream>>>(L, ctx);

    // ---- Mt[b][e][d] = sum_f Wo[f][e] * ctx[b][d][f]   (A=Wo^T, Bt=ctx)
    transpose_w<<<twg, twb, 0, stream>>>(Wo, Wt);
    gemm_bt<1, 0><<<dim3(8, 8, B_), blk, 0, stream>>>(Wt, ctx, Mt, nullptr,
        1024, 1024, 1024, 1024,
        0, (long)D_ * D_, (long)D_ * D_, 1.0f);

    // ---- out[b][n][e] = (sum_d 64 q[n,d] * Mt[b][e][d]) * 2^-25 + bo[e]
    // 2^-25 = (1/8 head scale) * (1/1024 D_OUT) * (1/64 q) * (1/64 k), all exact
    gemm_bt<2, 0><<<dim3(8, 32, B_), blk, 0, stream>>>(Qh, Mt, out, bo,
        1024, 1024, 1024, 1024,
        (long)N_ * D_, (long)D_ * D_, (long)N_ * D_,
        1.0f / 33554432.0f);
}

// Round 3
// 569.600 us; speedup vs baseline: 1.2074x; 1.2074x over previous
//
#include <hip/hip_runtime.h>

typedef _Float16 half_t;
typedef __attribute__((ext_vector_type(8))) _Float16 half8;
typedef __attribute__((ext_vector_type(4))) _Float16 half4;
typedef __attribute__((ext_vector_type(4))) float f32x4;

#define B_ 4
#define N_ 4096
#define D_ 1024
#define R_ (B_ * N_) // 16384

// ---------------------------------------------------------------------------
// async global->LDS, 16B per lane. LDS dest must be wave-uniform base + lane*16.
__device__ __forceinline__ void gload_lds16(const half_t* g, half_t* l) {
    __builtin_amdgcn_global_load_lds(
        (const __attribute__((address_space(1))) unsigned int*)g,
        (__attribute__((address_space(3))) unsigned int*)l, 16, 0, 0);
}

// ---------------------------------------------------------------------------
// C[m,n] = sum_k A[m,k] * Bt[n,k]   (A row-major [M,K], B given transposed [N,K])
// 128x128 tile, BK=32, 256 threads (4 waves, each 64x64 = 4x4 MFMA 16x16x32).
// Contiguous-lane staging (4 lanes cover one 64B row segment -> TA-coalesced);
// LDS row-major [128][32]; fragment ds_read_b128 has moderate bank aliasing
// (measured ~4e6 cyc/dispatch in R1 -- cheaper than scattering the global side, R2).
// DOUBLE-BUFFERED: prefetch tile k+1 into buf^1 BEFORE computing tile k from
// buf^0; single __syncthreads per iter drains the prefetch after compute has
// covered most of its latency.
// EPI: 0 = fp32 C, 1 = f16 C, 2 = fp32 C + bias (bias indexed by column)
// ZSHIFT: blockIdx.z = (batch << ZSHIFT) | ksplit; k window = ksplit*K .. +K.
//         C offset uses full blockIdx.z (partials laid out per z).
template <int EPI, int ZSHIFT>
__global__ __launch_bounds__(256) void gemm_bt(
    const half_t* __restrict__ A, const half_t* __restrict__ Bt,
    void* __restrict__ Cv, const float* __restrict__ bias,
    int lda, int ldb, int ldc, int K,
    long sA, long sB, long sC, float scale)
{
    __shared__ __align__(16) half_t As[2][128 * 32];
    __shared__ __align__(16) half_t Bs[2][128 * 32];

    const int t = threadIdx.x;
    const int wave = t >> 6;
    const int lane = t & 63;
    const int l15 = lane & 15;
    const int q = lane >> 4;
    const int m0 = blockIdx.y * 128;
    const int n0 = blockIdx.x * 128;
    const long zb = blockIdx.z >> ZSHIFT;
    const int zs = blockIdx.z & ((1 << ZSHIFT) - 1);

    // contiguous staging: 4 lanes x 16B = one 64B row segment
    const int r0 = t >> 2;
    const int c0 = (t & 3) * 8;

    const half_t* a0 = A + zb * sA + (long)(m0 + r0) * lda + zs * K + c0;
    const half_t* a1 = a0 + 64 * (long)lda;
    const half_t* b0 = Bt + zb * sB + (long)(n0 + r0) * ldb + zs * K + c0;
    const half_t* b1 = b0 + 64 * (long)ldb;

    f32x4 acc[4][4] = {};

    const int wr = (wave >> 1) * 64;
    const int wc = (wave & 1) * 64;

    // prologue: stage tile 0 into buffer 0
    gload_lds16(a0, As[0] + t * 8);
    gload_lds16(a1, As[0] + (t + 256) * 8);
    gload_lds16(b0, Bs[0] + t * 8);
    gload_lds16(b1, Bs[0] + (t + 256) * 8);
    __syncthreads();

    const int nk = K >> 5;
    for (int ki = 0; ki < nk; ki++) {
        const int cur = ki & 1;
        const int nxt = cur ^ 1;
        if (ki + 1 < nk) {
            const int k0 = (ki + 1) * 32;
            gload_lds16(a0 + k0, As[nxt] + t * 8);
            gload_lds16(a1 + k0, As[nxt] + (t + 256) * 8);
            gload_lds16(b0 + k0, Bs[nxt] + t * 8);
            gload_lds16(b1 + k0, Bs[nxt] + (t + 256) * 8);
        }

        half8 af[4], bfr[4];
#pragma unroll
        for (int i = 0; i < 4; i++)
            af[i] = *(const half8*)(As[cur] + (wr + i * 16 + l15) * 32 + q * 8);
#pragma unroll
        for (int j = 0; j < 4; j++)
            bfr[j] = *(const half8*)(Bs[cur] + (wc + j * 16 + l15) * 32 + q * 8);
#pragma unroll
        for (int i = 0; i < 4; i++)
#pragma unroll
            for (int j = 0; j < 4; j++)
                acc[i][j] = __builtin_amdgcn_mfma_f32_16x16x32_f16(af[i], bfr[j], acc[i][j], 0, 0, 0);
        __syncthreads(); // drains prefetch (vmcnt) + cur reads; next iter flips buffers
    }

    if (EPI == 1) {
        half_t* C = (half_t*)Cv + (long)blockIdx.z * sC + (long)m0 * ldc + n0;
#pragma unroll
        for (int i = 0; i < 4; i++)
#pragma unroll
            for (int j = 0; j < 4; j++) {
                const int col = wc + j * 16 + l15;
#pragma unroll
                for (int r = 0; r < 4; r++) {
                    const int row = wr + i * 16 + q * 4 + r;
                    C[(long)row * ldc + col] = (half_t)(acc[i][j][r] * scale);
                }
            }
    } else {
        float* C = (float*)Cv + (long)blockIdx.z * sC + (long)m0 * ldc + n0;
#pragma unroll
        for (int i = 0; i < 4; i++)
#pragma unroll
            for (int j = 0; j < 4; j++) {
                const int col = wc + j * 16 + l15;
                const float bv = (EPI == 2) ? bias[n0 + col] : 0.0f;
#pragma unroll
                for (int r = 0; r < 4; r++) {
                    const int row = wr + i * 16 + q * 4 + r;
                    C[(long)row * ldc + col] = acc[i][j][r] * scale + bv;
                }
            }
    }
}

// ---------------------------------------------------------------------------
// sum 4 split-K fp32 partials -> f16. P laid [z = b*4+s][1M floats], out [b][1M].
__global__ __launch_bounds__(256) void ctx_reduce(
    const float* __restrict__ P, half_t* __restrict__ ctx)
{
    const long i = ((long)blockIdx.x * 256 + threadIdx.x) * 4;
    const long b = i >> 20;
    const long idx = i & ((1L << 20) - 1);
    const float* p = P + (b * 4) * (1L << 20) + idx;
    const float4 s0 = *(const float4*)(p);
    const float4 s1 = *(const float4*)(p + (1L << 20));
    const float4 s2 = *(const float4*)(p + 2 * (1L << 20));
    const float4 s3 = *(const float4*)(p + 3 * (1L << 20));
    half4 o = {(half_t)(s0.x + s1.x + s2.x + s3.x),
               (half_t)(s0.y + s1.y + s2.y + s3.y),
               (half_t)(s0.z + s1.z + s2.z + s3.z),
               (half_t)(s0.w + s1.w + s2.w + s3.w)};
    *(half4*)(ctx + i) = o;
}

// ---------------------------------------------------------------------------
// fp32 -> f16 elementwise (8 elems/thread)
__global__ __launch_bounds__(256) void convert_f32_f16(
    const float* __restrict__ in, half_t* __restrict__ out)
{
    const long i = ((long)blockIdx.x * 256 + threadIdx.x) * 8;
    const float4 a = *(const float4*)(in + i);
    const float4 b = *(const float4*)(in + i + 4);
    half8 o = {(half_t)a.x, (half_t)a.y, (half_t)a.z, (half_t)a.w,
               (half_t)b.x, (half_t)b.y, (half_t)b.z, (half_t)b.w};
    *(half8*)(out + i) = o;
}

// ---------------------------------------------------------------------------
// 1024x1024 fp32 -> f16 transposed (Wt[j][i] = W[i][j]); block (32,8)
__global__ void transpose_w(const float* __restrict__ W, half_t* __restrict__ Wt)
{
    __shared__ float tile[32][33];
    const int tx = threadIdx.x, ty = threadIdx.y;
    const int bx = blockIdx.x * 32, by = blockIdx.y * 32;
#pragma unroll
    for (int yy = ty; yy < 32; yy += 8)
        tile[yy][tx] = W[(long)(by + yy) * 1024 + bx + tx];
    __syncthreads();
#pragma unroll
    for (int yy = ty; yy < 32; yy += 8)
        Wt[(long)(bx + yy) * 1024 + by + tx] = (half_t)tile[tx][yy];
}

// ---------------------------------------------------------------------------
// row softmax over 1024 features; one block per row. Output scaled by 64 (f16
// subnormal guard; compensated in final epilogue scale).
__global__ __launch_bounds__(256) void softmax_rows(
    const float* __restrict__ L, half_t* __restrict__ Qh)
{
    const int r = blockIdx.x;
    const int t = threadIdx.x;
    const float4 x = ((const float4*)(L + (long)r * 1024))[t];
    float m = fmaxf(fmaxf(x.x, x.y), fmaxf(x.z, x.w));
#pragma unroll
    for (int o = 32; o > 0; o >>= 1) m = fmaxf(m, __shfl_xor(m, o, 64));
    __shared__ float redm[4], reds[4];
    const int wave = t >> 6;
    if ((t & 63) == 0) redm[wave] = m;
    __syncthreads();
    m = fmaxf(fmaxf(redm[0], redm[1]), fmaxf(redm[2], redm[3]));
    const float e0 = __expf(x.x - m), e1 = __expf(x.y - m),
                e2 = __expf(x.z - m), e3 = __expf(x.w - m);
    float s = e0 + e1 + e2 + e3;
#pragma unroll
    for (int o = 32; o > 0; o >>= 1) s += __shfl_xor(s, o, 64);
    if ((t & 63) == 0) reds[wave] = s;
    __syncthreads();
    s = reds[0] + reds[1] + reds[2] + reds[3];
    const float rs = 64.0f / s;
    half4 o4 = {(half_t)(e0 * rs), (half_t)(e1 * rs),
                (half_t)(e2 * rs), (half_t)(e3 * rs)};
    ((half4*)(Qh + (long)r * 1024))[t] = o4;
}

// ---------------------------------------------------------------------------
// column softmax stats over N per (b,d): partial online max/sum per 256-row chunk
__global__ __launch_bounds__(256) void colstat1(
    const float* __restrict__ L, float* __restrict__ pm, float* __restrict__ ps)
{
    const int t = threadIdx.x;
    const int d = blockIdx.x * 256 + t;
    const int nc = blockIdx.y, b = blockIdx.z;
    const float* p = L + ((long)(b * N_ + nc * 256)) * 1024 + d;
    float m = -1e30f, s = 0.0f;
    for (int i = 0; i < 256; i++) {
        const float x = p[(long)i * 1024];
        const float nm = fmaxf(m, x);
        s = s * __expf(m - nm) + __expf(x - nm);
        m = nm;
    }
    const int o = (b * 16 + nc) * 1024 + d;
    pm[o] = m;
    ps[o] = s;
}

__global__ __launch_bounds__(256) void colstat2(
    const float* __restrict__ pm, const float* __restrict__ ps,
    float* __restrict__ cmax, float* __restrict__ crcp)
{
    const int c = blockIdx.x * 256 + threadIdx.x; // [0, 4096)
    const int b = c >> 10, d = c & 1023;
    float m = -1e30f;
#pragma unroll
    for (int j = 0; j < 16; j++) m = fmaxf(m, pm[(b * 16 + j) * 1024 + d]);
    float s = 0.0f;
#pragma unroll
    for (int j = 0; j < 16; j++)
        s += ps[(b * 16 + j) * 1024 + d] * __expf(pm[(b * 16 + j) * 1024 + d] - m);
    cmax[c] = m;
    crcp[c] = 1.0f / s;
}

// ---------------------------------------------------------------------------
// [B,N,D] fp32 -> [B,D,N] f16, optionally applying column softmax (exp/Z * 64)
template <bool SM>
__global__ __launch_bounds__(256) void transpose_nd(
    const float* __restrict__ L, half_t* __restrict__ Out,
    const float* __restrict__ cmax, const float* __restrict__ crcp)
{
    __shared__ half_t tile[64][66]; // 66: odd word stride -> conflict-free
    const int t = threadIdx.x;
    const int n0 = blockIdx.x * 64, d0 = blockIdx.y * 64;
    const int b = blockIdx.z;
    const float* src = L + ((long)(b * N_ + n0)) * 1024 + d0;
#pragma unroll
    for (int i = 0; i < 16; i++) {
        const int idx = i * 256 + t;
        const int nl = idx >> 6, dl = idx & 63;
        float x = src[(long)nl * 1024 + dl];
        if (SM)
            x = __expf(x - cmax[b * 1024 + d0 + dl]) * (64.0f * crcp[b * 1024 + d0 + dl]);
        tile[dl][nl] = (half_t)x;
    }
    __syncthreads();
    half_t* dst = Out + ((long)(b * 1024 + d0)) * (long)N_ + n0;
#pragma unroll
    for (int i = 0; i < 16; i++) {
        const int idx = i * 256 + t;
        const int dl = idx >> 6, nl = idx & 63;
        dst[(long)dl * N_ + nl] = tile[dl][nl];
    }
}

// ---------------------------------------------------------------------------
extern "C" void kernel_launch(void* const* d_in, const int* in_sizes, int n_in,
                              void* d_out, int out_size, void* d_ws, size_t ws_size,
                              hipStream_t stream)
{
    const float* x  = (const float*)d_in[0];
    const float* Wq = (const float*)d_in[1];
    const float* Wk = (const float*)d_in[2];
    const float* Wv = (const float*)d_in[3];
    const float* Wo = (const float*)d_in[4];
    const float* bo = (const float*)d_in[5];
    float* out = (float*)d_out;

    char* w = (char*)d_ws;
    half_t* Xh  = (half_t*)w; w += (size_t)R_ * D_ * 2;       // 32 MiB
    float*  L   = (float*)w;  w += (size_t)R_ * D_ * 4;       // 64 MiB (logits, then split-K partials)
    half_t* Qh  = (half_t*)w; w += (size_t)R_ * D_ * 2;       // 32 MiB (q * 64)
    half_t* Kt  = (half_t*)w; w += (size_t)R_ * D_ * 2;       // 32 MiB [B,D,N] (k * 64)
    half_t* Vt  = (half_t*)w; w += (size_t)R_ * D_ * 2;       // 32 MiB [B,D,N]
    half_t* Wt  = (half_t*)w; w += (size_t)D_ * D_ * 2;       // 2 MiB (reused)
    half_t* ctx = (half_t*)w; w += (size_t)B_ * D_ * D_ * 2;  // 8 MiB (64 * K^T V)
    half_t* Mt  = (half_t*)w; w += (size_t)B_ * D_ * D_ * 2;  // 8 MiB (64 * (ctx Wo)^T)
    float*  pm  = (float*)w;  w += (size_t)B_ * 16 * D_ * 4;
    float*  ps  = (float*)w;  w += (size_t)B_ * 16 * D_ * 4;
    float*  cmx = (float*)w;  w += (size_t)B_ * D_ * 4;
    float*  crp = (float*)w;  w += (size_t)B_ * D_ * 4;
    (void)ws_size; (void)in_sizes; (void)n_in; (void)out_size;

    const dim3 blk(256);
    const dim3 twb(32, 8), twg(32, 32);

    convert_f32_f16<<<R_ * D_ / (256 * 8), blk, 0, stream>>>(x, Xh);

    // ---- Q path
    transpose_w<<<twg, twb, 0, stream>>>(Wq, Wt);
    gemm_bt<0, 0><<<dim3(8, 128, 1), blk, 0, stream>>>(Xh, Wt, L, nullptr,
        1024, 1024, 1024, 1024, 0, 0, 0, 1.0f);
    softmax_rows<<<R_, blk, 0, stream>>>(L, Qh);

    // ---- K path (column softmax over sequence, then transpose to [B,D,N])
    transpose_w<<<twg, twb, 0, stream>>>(Wk, Wt);
    gemm_bt<0, 0><<<dim3(8, 128, 1), blk, 0, stream>>>(Xh, Wt, L, nullptr,
        1024, 1024, 1024, 1024, 0, 0, 0, 1.0f);
    colstat1<<<dim3(4, 16, B_), blk, 0, stream>>>(L, pm, ps);
    colstat2<<<16, blk, 0, stream>>>(pm, ps, cmx, crp);
    transpose_nd<true><<<dim3(64, 16, B_), blk, 0, stream>>>(L, Kt, cmx, crp);

    // ---- V path (transpose to [B,D,N])
    transpose_w<<<twg, twb, 0, stream>>>(Wv, Wt);
    gemm_bt<0, 0><<<dim3(8, 128, 1), blk, 0, stream>>>(Xh, Wt, L, nullptr,
        1024, 1024, 1024, 1024, 0, 0, 0, 1.0f);
    transpose_nd<false><<<dim3(64, 16, B_), blk, 0, stream>>>(L, Vt, nullptr, nullptr);

    // ---- ctx[b][d][e] = sum_n (64 k[n,d]) v[n,e], split-K=4 (z = b*4+s)
    gemm_bt<0, 2><<<dim3(8, 8, 16), blk, 0, stream>>>(Kt, Vt, L, nullptr,
        N_, N_, 1024, N_ / 4,
        (long)D_ * N_, (long)D_ * N_, 1L << 20, 1.0f);
    ctx_reduce<<<4096, blk, 0, stream>>>(L, ctx);

    // ---- Mt[b][e][d] = sum_f Wo[f][e] * ctx[b][d][f], split-K=4 (A=Wo^T, Bt=ctx)
    transpose_w<<<twg, twb, 0, stream>>>(Wo, Wt);
    gemm_bt<0, 2><<<dim3(8, 8, 16), blk, 0, stream>>>(Wt, ctx, L, nullptr,
        1024, 1024, 1024, 1024 / 4,
        0, (long)D_ * D_, 1L << 20, 1.0f);
    ctx_reduce<<<4096, blk, 0, stream>>>(L, Mt);

    // ---- out[b][n][e] = (sum_d 64 q[n,d] * Mt[b][e][d]) * 2^-25 + bo[e]
    // 2^-25 = (1/8 head scale) * (1/1024 D_OUT) * (1/64 q) * (1/64 k), all exact
    gemm_bt<2, 0><<<dim3(8, 32, B_), blk, 0, stream>>>(Qh, Mt, out, bo,
        1024, 1024, 1024, 1024,
        (long)N_ * D_, (long)D_ * D_, (long)N_ * D_,
        1.0f / 33554432.0f);
}

// Round 4
// 521.948 us; speedup vs baseline: 1.3176x; 1.0913x over previous
//
#include <hip/hip_runtime.h>

typedef _Float16 half_t;
typedef __attribute__((ext_vector_type(8))) _Float16 half8;
typedef __attribute__((ext_vector_type(4))) _Float16 half4;
typedef __attribute__((ext_vector_type(4))) float f32x4;

#define B_ 4
#define N_ 4096
#define D_ 1024
#define R_ (B_ * N_) // 16384

// ---------------------------------------------------------------------------
// async global->LDS, 16B per lane. LDS dest must be wave-uniform base + lane*16.
__device__ __forceinline__ void gload_lds16(const half_t* g, half_t* l) {
    __builtin_amdgcn_global_load_lds(
        (const __attribute__((address_space(1))) unsigned int*)g,
        (__attribute__((address_space(3))) unsigned int*)l, 16, 0, 0);
}

// ---------------------------------------------------------------------------
// C[m,n] = sum_k A[m,k] * Bt[n,k]   (A row-major [M,K], B given transposed [N,K])
// 128x128 tile, BK=32, 256 threads (4 waves, each 64x64 = 4x4 MFMA 16x16x32).
// Contiguous-lane staging; LDS double-buffered, prefetch-before-compute (R3: 96->70us).
// SWAP=1: m-tile = blockIdx.x (fastest) so the blocks sharing an A row-band get
// linear IDs = same (mod 8) -> same XCD -> A-band fetched once per device (R3:
// n-fastest order replicated A across all 8 XCD L2s, FETCH 135MB vs 34MB ideal).
// EPI: 0 = fp32 C, 1 = f16 C, 2 = fp32 C + bias (bias indexed by column)
// ZSHIFT: blockIdx.z = (batch << ZSHIFT) | ksplit; k window = ksplit*K .. +K.
template <int EPI, int ZSHIFT, int SWAP>
__global__ __launch_bounds__(256) void gemm_bt(
    const half_t* __restrict__ A, const half_t* __restrict__ Bt,
    void* __restrict__ Cv, const float* __restrict__ bias,
    int lda, int ldb, int ldc, int K,
    long sA, long sB, long sC, float scale)
{
    __shared__ __align__(16) half_t As[2][128 * 32];
    __shared__ __align__(16) half_t Bs[2][128 * 32];

    const int t = threadIdx.x;
    const int wave = t >> 6;
    const int lane = t & 63;
    const int l15 = lane & 15;
    const int q = lane >> 4;
    const int m0 = (SWAP ? blockIdx.x : blockIdx.y) * 128;
    const int n0 = (SWAP ? blockIdx.y : blockIdx.x) * 128;
    const long zb = blockIdx.z >> ZSHIFT;
    const int zs = blockIdx.z & ((1 << ZSHIFT) - 1);

    // contiguous staging: 4 lanes x 16B = one 64B row segment
    const int r0 = t >> 2;
    const int c0 = (t & 3) * 8;

    const half_t* a0 = A + zb * sA + (long)(m0 + r0) * lda + zs * K + c0;
    const half_t* a1 = a0 + 64 * (long)lda;
    const half_t* b0 = Bt + zb * sB + (long)(n0 + r0) * ldb + zs * K + c0;
    const half_t* b1 = b0 + 64 * (long)ldb;

    f32x4 acc[4][4] = {};

    const int wr = (wave >> 1) * 64;
    const int wc = (wave & 1) * 64;

    // prologue: stage tile 0 into buffer 0
    gload_lds16(a0, As[0] + t * 8);
    gload_lds16(a1, As[0] + (t + 256) * 8);
    gload_lds16(b0, Bs[0] + t * 8);
    gload_lds16(b1, Bs[0] + (t + 256) * 8);
    __syncthreads();

    const int nk = K >> 5;
    for (int ki = 0; ki < nk; ki++) {
        const int cur = ki & 1;
        const int nxt = cur ^ 1;
        if (ki + 1 < nk) {
            const int k0 = (ki + 1) * 32;
            gload_lds16(a0 + k0, As[nxt] + t * 8);
            gload_lds16(a1 + k0, As[nxt] + (t + 256) * 8);
            gload_lds16(b0 + k0, Bs[nxt] + t * 8);
            gload_lds16(b1 + k0, Bs[nxt] + (t + 256) * 8);
        }

        half8 af[4], bfr[4];
#pragma unroll
        for (int i = 0; i < 4; i++)
            af[i] = *(const half8*)(As[cur] + (wr + i * 16 + l15) * 32 + q * 8);
#pragma unroll
        for (int j = 0; j < 4; j++)
            bfr[j] = *(const half8*)(Bs[cur] + (wc + j * 16 + l15) * 32 + q * 8);
#pragma unroll
        for (int i = 0; i < 4; i++)
#pragma unroll
            for (int j = 0; j < 4; j++)
                acc[i][j] = __builtin_amdgcn_mfma_f32_16x16x32_f16(af[i], bfr[j], acc[i][j], 0, 0, 0);
        __syncthreads(); // drains prefetch; next iter flips buffers
    }

    if (EPI == 1) {
        half_t* C = (half_t*)Cv + (long)blockIdx.z * sC + (long)m0 * ldc + n0;
#pragma unroll
        for (int i = 0; i < 4; i++)
#pragma unroll
            for (int j = 0; j < 4; j++) {
                const int col = wc + j * 16 + l15;
#pragma unroll
                for (int r = 0; r < 4; r++) {
                    const int row = wr + i * 16 + q * 4 + r;
                    C[(long)row * ldc + col] = (half_t)(acc[i][j][r] * scale);
                }
            }
    } else {
        float* C = (float*)Cv + (long)blockIdx.z * sC + (long)m0 * ldc + n0;
#pragma unroll
        for (int i = 0; i < 4; i++)
#pragma unroll
            for (int j = 0; j < 4; j++) {
                const int col = wc + j * 16 + l15;
                const float bv = (EPI == 2) ? bias[n0 + col] : 0.0f;
#pragma unroll
                for (int r = 0; r < 4; r++) {
                    const int row = wr + i * 16 + q * 4 + r;
                    C[(long)row * ldc + col] = acc[i][j][r] * scale + bv;
                }
            }
    }
}

// ---------------------------------------------------------------------------
// sum 4 split-K fp32 partials -> f16. P laid [z = b*4+s][1M floats], out [b][1M].
__global__ __launch_bounds__(256) void ctx_reduce(
    const float* __restrict__ P, half_t* __restrict__ ctx)
{
    const long i = ((long)blockIdx.x * 256 + threadIdx.x) * 4;
    const long b = i >> 20;
    const long idx = i & ((1L << 20) - 1);
    const float* p = P + (b * 4) * (1L << 20) + idx;
    const float4 s0 = *(const float4*)(p);
    const float4 s1 = *(const float4*)(p + (1L << 20));
    const float4 s2 = *(const float4*)(p + 2 * (1L << 20));
    const float4 s3 = *(const float4*)(p + 3 * (1L << 20));
    half4 o = {(half_t)(s0.x + s1.x + s2.x + s3.x),
               (half_t)(s0.y + s1.y + s2.y + s3.y),
               (half_t)(s0.z + s1.z + s2.z + s3.z),
               (half_t)(s0.w + s1.w + s2.w + s3.w)};
    *(half4*)(ctx + i) = o;
}

// ---------------------------------------------------------------------------
// fp32 -> f16 elementwise (8 elems/thread)
__global__ __launch_bounds__(256) void convert_f32_f16(
    const float* __restrict__ in, half_t* __restrict__ out)
{
    const long i = ((long)blockIdx.x * 256 + threadIdx.x) * 8;
    const float4 a = *(const float4*)(in + i);
    const float4 b = *(const float4*)(in + i + 4);
    half8 o = {(half_t)a.x, (half_t)a.y, (half_t)a.z, (half_t)a.w,
               (half_t)b.x, (half_t)b.y, (half_t)b.z, (half_t)b.w};
    *(half8*)(out + i) = o;
}

// ---------------------------------------------------------------------------
// 1024x1024 fp32 -> f16 transposed (Wt[j][i] = W[i][j]); block (32,8)
__global__ void transpose_w(const float* __restrict__ W, half_t* __restrict__ Wt)
{
    __shared__ float tile[32][33];
    const int tx = threadIdx.x, ty = threadIdx.y;
    const int bx = blockIdx.x * 32, by = blockIdx.y * 32;
#pragma unroll
    for (int yy = ty; yy < 32; yy += 8)
        tile[yy][tx] = W[(long)(by + yy) * 1024 + bx + tx];
    __syncthreads();
#pragma unroll
    for (int yy = ty; yy < 32; yy += 8)
        Wt[(long)(bx + yy) * 1024 + by + tx] = (half_t)tile[tx][yy];
}

// ---------------------------------------------------------------------------
// row softmax over 1024 features (f16 logits in, fp32 math); one block per row.
// Output scaled by 64 (f16 subnormal guard; compensated in final epilogue).
__global__ __launch_bounds__(256) void softmax_rows(
    const half_t* __restrict__ L, half_t* __restrict__ Qh)
{
    const int r = blockIdx.x;
    const int t = threadIdx.x;
    const half4 xh = ((const half4*)(L + (long)r * 1024))[t];
    const float x0 = (float)xh[0], x1 = (float)xh[1],
                x2 = (float)xh[2], x3 = (float)xh[3];
    float m = fmaxf(fmaxf(x0, x1), fmaxf(x2, x3));
#pragma unroll
    for (int o = 32; o > 0; o >>= 1) m = fmaxf(m, __shfl_xor(m, o, 64));
    __shared__ float redm[4], reds[4];
    const int wave = t >> 6;
    if ((t & 63) == 0) redm[wave] = m;
    __syncthreads();
    m = fmaxf(fmaxf(redm[0], redm[1]), fmaxf(redm[2], redm[3]));
    const float e0 = __expf(x0 - m), e1 = __expf(x1 - m),
                e2 = __expf(x2 - m), e3 = __expf(x3 - m);
    float s = e0 + e1 + e2 + e3;
#pragma unroll
    for (int o = 32; o > 0; o >>= 1) s += __shfl_xor(s, o, 64);
    if ((t & 63) == 0) reds[wave] = s;
    __syncthreads();
    s = reds[0] + reds[1] + reds[2] + reds[3];
    const float rs = 64.0f / s;
    half4 o4 = {(half_t)(e0 * rs), (half_t)(e1 * rs),
                (half_t)(e2 * rs), (half_t)(e3 * rs)};
    ((half4*)(Qh + (long)r * 1024))[t] = o4;
}

// ---------------------------------------------------------------------------
// column softmax stats over N per (b,d): partial online max/sum per 256-row chunk
__global__ __launch_bounds__(256) void colstat1(
    const half_t* __restrict__ L, float* __restrict__ pm, float* __restrict__ ps)
{
    const int t = threadIdx.x;
    const int d = blockIdx.x * 256 + t;
    const int nc = blockIdx.y, b = blockIdx.z;
    const half_t* p = L + ((long)(b * N_ + nc * 256)) * 1024 + d;
    float m = -1e30f, s = 0.0f;
    for (int i = 0; i < 256; i++) {
        const float x = (float)p[(long)i * 1024];
        const float nm = fmaxf(m, x);
        s = s * __expf(m - nm) + __expf(x - nm);
        m = nm;
    }
    const int o = (b * 16 + nc) * 1024 + d;
    pm[o] = m;
    ps[o] = s;
}

__global__ __launch_bounds__(256) void colstat2(
    const float* __restrict__ pm, const float* __restrict__ ps,
    float* __restrict__ cmax, float* __restrict__ crcp)
{
    const int c = blockIdx.x * 256 + threadIdx.x; // [0, 4096)
    const int b = c >> 10, d = c & 1023;
    float m = -1e30f;
#pragma unroll
    for (int j = 0; j < 16; j++) m = fmaxf(m, pm[(b * 16 + j) * 1024 + d]);
    float s = 0.0f;
#pragma unroll
    for (int j = 0; j < 16; j++)
        s += ps[(b * 16 + j) * 1024 + d] * __expf(pm[(b * 16 + j) * 1024 + d] - m);
    cmax[c] = m;
    crcp[c] = 1.0f / s;
}

// ---------------------------------------------------------------------------
// [B,N,D] f16 -> [B,D,N] f16, optionally applying column softmax (exp/Z * 64)
template <bool SM>
__global__ __launch_bounds__(256) void transpose_nd(
    const half_t* __restrict__ L, half_t* __restrict__ Out,
    const float* __restrict__ cmax, const float* __restrict__ crcp)
{
    __shared__ half_t tile[64][66]; // odd word stride -> conflict-free
    const int t = threadIdx.x;
    const int n0 = blockIdx.x * 64, d0 = blockIdx.y * 64;
    const int b = blockIdx.z;
    const half_t* src = L + ((long)(b * N_ + n0)) * 1024 + d0;
#pragma unroll
    for (int i = 0; i < 16; i++) {
        const int idx = i * 256 + t;
        const int nl = idx >> 6, dl = idx & 63;
        float x = (float)src[(long)nl * 1024 + dl];
        if (SM)
            x = __expf(x - cmax[b * 1024 + d0 + dl]) * (64.0f * crcp[b * 1024 + d0 + dl]);
        tile[dl][nl] = (half_t)x;
    }
    __syncthreads();
    half_t* dst = Out + ((long)(b * 1024 + d0)) * (long)N_ + n0;
#pragma unroll
    for (int i = 0; i < 16; i++) {
        const int idx = i * 256 + t;
        const int dl = idx >> 6, nl = idx & 63;
        dst[(long)dl * N_ + nl] = tile[dl][nl];
    }
}

// ---------------------------------------------------------------------------
extern "C" void kernel_launch(void* const* d_in, const int* in_sizes, int n_in,
                              void* d_out, int out_size, void* d_ws, size_t ws_size,
                              hipStream_t stream)
{
    const float* x  = (const float*)d_in[0];
    const float* Wq = (const float*)d_in[1];
    const float* Wk = (const float*)d_in[2];
    const float* Wv = (const float*)d_in[3];
    const float* Wo = (const float*)d_in[4];
    const float* bo = (const float*)d_in[5];
    float* out = (float*)d_out;

    // Region 0 (64 MiB): Xh (32) + Lh (32) while building Q/K/V; both dead by
    // the ctx GEMM, then the same region holds the fp32 split-K partials P.
    char* w = (char*)d_ws;
    half_t* Xh  = (half_t*)w;                          // 32 MiB (x as f16)
    half_t* Lh  = (half_t*)(w + ((size_t)R_ * D_ * 2)); // 32 MiB (f16 logits, serial Q/K/V)
    float*  P   = (float*)w;                           // 64 MiB (split-K partials, later)
    w += (size_t)R_ * D_ * 4;
    half_t* Qh  = (half_t*)w; w += (size_t)R_ * D_ * 2;       // 32 MiB (q * 64)
    half_t* Kt  = (half_t*)w; w += (size_t)R_ * D_ * 2;       // 32 MiB [B,D,N] (k * 64)
    half_t* Vt  = (half_t*)w; w += (size_t)R_ * D_ * 2;       // 32 MiB [B,D,N]
    half_t* Wt  = (half_t*)w; w += (size_t)D_ * D_ * 2;       // 2 MiB (reused)
    half_t* ctx = (half_t*)w; w += (size_t)B_ * D_ * D_ * 2;  // 8 MiB (64 * K^T V)
    half_t* Mt  = (half_t*)w; w += (size_t)B_ * D_ * D_ * 2;  // 8 MiB (64 * (ctx Wo)^T)
    float*  pm  = (float*)w;  w += (size_t)B_ * 16 * D_ * 4;
    float*  ps  = (float*)w;  w += (size_t)B_ * 16 * D_ * 4;
    float*  cmx = (float*)w;  w += (size_t)B_ * D_ * 4;
    float*  crp = (float*)w;  w += (size_t)B_ * D_ * 4;
    (void)ws_size; (void)in_sizes; (void)n_in; (void)out_size;

    const dim3 blk(256);
    const dim3 twb(32, 8), twg(32, 32);

    convert_f32_f16<<<R_ * D_ / (256 * 8), blk, 0, stream>>>(x, Xh);

    // ---- Q path (f16 logits)
    transpose_w<<<twg, twb, 0, stream>>>(Wq, Wt);
    gemm_bt<1, 0, 1><<<dim3(128, 8, 1), blk, 0, stream>>>(Xh, Wt, Lh, nullptr,
        1024, 1024, 1024, 1024, 0, 0, 0, 1.0f);
    softmax_rows<<<R_, blk, 0, stream>>>(Lh, Qh);

    // ---- K path (column softmax over sequence, then transpose to [B,D,N])
    transpose_w<<<twg, twb, 0, stream>>>(Wk, Wt);
    gemm_bt<1, 0, 1><<<dim3(128, 8, 1), blk, 0, stream>>>(Xh, Wt, Lh, nullptr,
        1024, 1024, 1024, 1024, 0, 0, 0, 1.0f);
    colstat1<<<dim3(4, 16, B_), blk, 0, stream>>>(Lh, pm, ps);
    colstat2<<<16, blk, 0, stream>>>(pm, ps, cmx, crp);
    transpose_nd<true><<<dim3(64, 16, B_), blk, 0, stream>>>(Lh, Kt, cmx, crp);

    // ---- V path (transpose to [B,D,N])
    transpose_w<<<twg, twb, 0, stream>>>(Wv, Wt);
    gemm_bt<1, 0, 1><<<dim3(128, 8, 1), blk, 0, stream>>>(Xh, Wt, Lh, nullptr,
        1024, 1024, 1024, 1024, 0, 0, 0, 1.0f);
    transpose_nd<false><<<dim3(64, 16, B_), blk, 0, stream>>>(Lh, Vt, nullptr, nullptr);

    // ---- ctx[b][d][e] = sum_n (64 k[n,d]) v[n,e], split-K=4 (z = b*4+s)
    // (Xh and Lh are dead now; their 64 MiB region holds the partials P)
    gemm_bt<0, 2, 1><<<dim3(8, 8, 16), blk, 0, stream>>>(Kt, Vt, P, nullptr,
        N_, N_, 1024, N_ / 4,
        (long)D_ * N_, (long)D_ * N_, 1L << 20, 1.0f);
    ctx_reduce<<<4096, blk, 0, stream>>>(P, ctx);

    // ---- Mt[b][e][d] = sum_f Wo[f][e] * ctx[b][d][f], split-K=4 (A=Wo^T, Bt=ctx)
    transpose_w<<<twg, twb, 0, stream>>>(Wo, Wt);
    gemm_bt<0, 2, 1><<<dim3(8, 8, 16), blk, 0, stream>>>(Wt, ctx, P, nullptr,
        1024, 1024, 1024, 1024 / 4,
        0, (long)D_ * D_, 1L << 20, 1.0f);
    ctx_reduce<<<4096, blk, 0, stream>>>(P, Mt);

    // ---- out[b][n][e] = (sum_d 64 q[n,d] * Mt[b][e][d]) * 2^-25 + bo[e]
    // 2^-25 = (1/8 head scale) * (1/1024 D_OUT) * (1/64 q) * (1/64 k), all exact
    gemm_bt<2, 0, 1><<<dim3(32, 8, B_), blk, 0, stream>>>(Qh, Mt, out, bo,
        1024, 1024, 1024, 1024,
        (long)N_ * D_, (long)D_ * D_, (long)N_ * D_,
        1.0f / 33554432.0f);
}

// Round 5
// 459.908 us; speedup vs baseline: 1.4954x; 1.1349x over previous
//
#include <hip/hip_runtime.h>

typedef _Float16 half_t;
typedef __attribute__((ext_vector_type(8))) _Float16 half8;
typedef __attribute__((ext_vector_type(4))) _Float16 half4;
typedef __attribute__((ext_vector_type(4))) float f32x4;

#define B_ 4
#define N_ 4096
#define D_ 1024
#define R_ (B_ * N_) // 16384

// ---------------------------------------------------------------------------
// async global->LDS, 16B per lane. LDS dest must be wave-uniform base + lane*16.
__device__ __forceinline__ void gload_lds16(const half_t* g, half_t* l) {
    __builtin_amdgcn_global_load_lds(
        (const __attribute__((address_space(1))) unsigned int*)g,
        (__attribute__((address_space(3))) unsigned int*)l, 16, 0, 0);
}

// ---------------------------------------------------------------------------
// C[m,n] = sum_k A[m,k] * Bt[n,k]   (A row-major [M,K], B given transposed [N,K])
// 128x128 tile, BK=32, 256 threads (4 waves, each 64x64 = 4x4 MFMA 16x16x32).
// Contiguous-lane staging; LDS double-buffered, prefetch-before-compute.
// SWAP=1: m-tile = blockIdx.x fastest -> same-A-band blocks share an XCD (use
//   when A is the big operand). SWAP=0: n-tile fastest; same-B-band blocks
//   then sit at ID stride gridDim.x (mult of 8) -> same XCD (use when B big).
// EPI: 0 = fp32 C, 1 = f16 C, 2 = fp32 C + bias (bias indexed by column)
// ZSHIFT: blockIdx.z = (batch << ZSHIFT) | ksplit; k window = ksplit*K .. +K.
//         C offset uses full blockIdx.z (split-K partials laid out per z).
template <int EPI, int ZSHIFT, int SWAP>
__global__ __launch_bounds__(256) void gemm_bt(
    const half_t* __restrict__ A, const half_t* __restrict__ Bt,
    void* __restrict__ Cv, const float* __restrict__ bias,
    int lda, int ldb, int ldc, int K,
    long sA, long sB, long sC, float scale)
{
    __shared__ __align__(16) half_t As[2][128 * 32];
    __shared__ __align__(16) half_t Bs[2][128 * 32];

    const int t = threadIdx.x;
    const int wave = t >> 6;
    const int lane = t & 63;
    const int l15 = lane & 15;
    const int q = lane >> 4;
    const int m0 = (SWAP ? blockIdx.x : blockIdx.y) * 128;
    const int n0 = (SWAP ? blockIdx.y : blockIdx.x) * 128;
    const long zb = blockIdx.z >> ZSHIFT;
    const int zs = blockIdx.z & ((1 << ZSHIFT) - 1);

    // contiguous staging: 4 lanes x 16B = one 64B row segment
    const int r0 = t >> 2;
    const int c0 = (t & 3) * 8;

    const half_t* a0 = A + zb * sA + (long)(m0 + r0) * lda + zs * K + c0;
    const half_t* a1 = a0 + 64 * (long)lda;
    const half_t* b0 = Bt + zb * sB + (long)(n0 + r0) * ldb + zs * K + c0;
    const half_t* b1 = b0 + 64 * (long)ldb;

    f32x4 acc[4][4] = {};

    const int wr = (wave >> 1) * 64;
    const int wc = (wave & 1) * 64;

    // prologue: stage tile 0 into buffer 0
    gload_lds16(a0, As[0] + t * 8);
    gload_lds16(a1, As[0] + (t + 256) * 8);
    gload_lds16(b0, Bs[0] + t * 8);
    gload_lds16(b1, Bs[0] + (t + 256) * 8);
    __syncthreads();

    const int nk = K >> 5;
    for (int ki = 0; ki < nk; ki++) {
        const int cur = ki & 1;
        const int nxt = cur ^ 1;
        if (ki + 1 < nk) {
            const int k0 = (ki + 1) * 32;
            gload_lds16(a0 + k0, As[nxt] + t * 8);
            gload_lds16(a1 + k0, As[nxt] + (t + 256) * 8);
            gload_lds16(b0 + k0, Bs[nxt] + t * 8);
            gload_lds16(b1 + k0, Bs[nxt] + (t + 256) * 8);
        }

        half8 af[4], bfr[4];
#pragma unroll
        for (int i = 0; i < 4; i++)
            af[i] = *(const half8*)(As[cur] + (wr + i * 16 + l15) * 32 + q * 8);
#pragma unroll
        for (int j = 0; j < 4; j++)
            bfr[j] = *(const half8*)(Bs[cur] + (wc + j * 16 + l15) * 32 + q * 8);
#pragma unroll
        for (int i = 0; i < 4; i++)
#pragma unroll
            for (int j = 0; j < 4; j++)
                acc[i][j] = __builtin_amdgcn_mfma_f32_16x16x32_f16(af[i], bfr[j], acc[i][j], 0, 0, 0);
        __syncthreads(); // drains prefetch; next iter flips buffers
    }

    if (EPI == 1) {
        half_t* C = (half_t*)Cv + (long)blockIdx.z * sC + (long)m0 * ldc + n0;
#pragma unroll
        for (int i = 0; i < 4; i++)
#pragma unroll
            for (int j = 0; j < 4; j++) {
                const int col = wc + j * 16 + l15;
#pragma unroll
                for (int r = 0; r < 4; r++) {
                    const int row = wr + i * 16 + q * 4 + r;
                    C[(long)row * ldc + col] = (half_t)(acc[i][j][r] * scale);
                }
            }
    } else {
        float* C = (float*)Cv + (long)blockIdx.z * sC + (long)m0 * ldc + n0;
#pragma unroll
        for (int i = 0; i < 4; i++)
#pragma unroll
            for (int j = 0; j < 4; j++) {
                const int col = wc + j * 16 + l15;
                const float bv = (EPI == 2) ? bias[n0 + col] : 0.0f;
#pragma unroll
                for (int r = 0; r < 4; r++) {
                    const int row = wr + i * 16 + q * 4 + r;
                    C[(long)row * ldc + col] = acc[i][j][r] * scale + bv;
                }
            }
    }
}

// ---------------------------------------------------------------------------
// sum 4 split-K f16 partials (fp32 math) -> f16. P laid [z = b*4+s][1M halfs].
__global__ __launch_bounds__(256) void ctx_reduce_h(
    const half_t* __restrict__ P, half_t* __restrict__ ctx)
{
    const long i = ((long)blockIdx.x * 256 + threadIdx.x) * 8;
    const long b = i >> 20;
    const long idx = i & ((1L << 20) - 1);
    const half_t* p = P + (b * 4) * (1L << 20) + idx;
    const half8 s0 = *(const half8*)(p);
    const half8 s1 = *(const half8*)(p + (1L << 20));
    const half8 s2 = *(const half8*)(p + 2 * (1L << 20));
    const half8 s3 = *(const half8*)(p + 3 * (1L << 20));
    half8 o;
#pragma unroll
    for (int j = 0; j < 8; j++)
        o[j] = (half_t)((float)s0[j] + (float)s1[j] + (float)s2[j] + (float)s3[j]);
    *(half8*)(ctx + i) = o;
}

// ---------------------------------------------------------------------------
// fp32 -> f16 elementwise (8 elems/thread)
__global__ __launch_bounds__(256) void convert_f32_f16(
    const float* __restrict__ in, half_t* __restrict__ out)
{
    const long i = ((long)blockIdx.x * 256 + threadIdx.x) * 8;
    const float4 a = *(const float4*)(in + i);
    const float4 b = *(const float4*)(in + i + 4);
    half8 o = {(half_t)a.x, (half_t)a.y, (half_t)a.z, (half_t)a.w,
               (half_t)b.x, (half_t)b.y, (half_t)b.z, (half_t)b.w};
    *(half8*)(out + i) = o;
}

// ---------------------------------------------------------------------------
// four 1024x1024 fp32 -> f16 transposed in one launch (z selects matrix)
__global__ void transpose_w4(const float* __restrict__ W0, const float* __restrict__ W1,
                             const float* __restrict__ W2, const float* __restrict__ W3,
                             half_t* __restrict__ Wt)
{
    __shared__ float tile[32][33];
    const float* W = blockIdx.z == 0 ? W0 : blockIdx.z == 1 ? W1
                   : blockIdx.z == 2 ? W2 : W3;
    half_t* dst = Wt + (size_t)blockIdx.z * 1024 * 1024;
    const int tx = threadIdx.x, ty = threadIdx.y;
    const int bx = blockIdx.x * 32, by = blockIdx.y * 32;
#pragma unroll
    for (int yy = ty; yy < 32; yy += 8)
        tile[yy][tx] = W[(long)(by + yy) * 1024 + bx + tx];
    __syncthreads();
#pragma unroll
    for (int yy = ty; yy < 32; yy += 8)
        dst[(long)(bx + yy) * 1024 + by + tx] = (half_t)tile[tx][yy];
}

// ---------------------------------------------------------------------------
// row softmax over 1024 features (f16 in, fp32 math); one block per row.
// Output scaled by 64 (f16 subnormal guard; compensated in final epilogue).
__global__ __launch_bounds__(256) void softmax_rows(
    const half_t* __restrict__ L, half_t* __restrict__ Qh)
{
    const int r = blockIdx.x;
    const int t = threadIdx.x;
    const half4 xh = ((const half4*)(L + (long)r * 1024))[t];
    const float x0 = (float)xh[0], x1 = (float)xh[1],
                x2 = (float)xh[2], x3 = (float)xh[3];
    float m = fmaxf(fmaxf(x0, x1), fmaxf(x2, x3));
#pragma unroll
    for (int o = 32; o > 0; o >>= 1) m = fmaxf(m, __shfl_xor(m, o, 64));
    __shared__ float redm[4], reds[4];
    const int wave = t >> 6;
    if ((t & 63) == 0) redm[wave] = m;
    __syncthreads();
    m = fmaxf(fmaxf(redm[0], redm[1]), fmaxf(redm[2], redm[3]));
    const float e0 = __expf(x0 - m), e1 = __expf(x1 - m),
                e2 = __expf(x2 - m), e3 = __expf(x3 - m);
    float s = e0 + e1 + e2 + e3;
#pragma unroll
    for (int o = 32; o > 0; o >>= 1) s += __shfl_xor(s, o, 64);
    if ((t & 63) == 0) reds[wave] = s;
    __syncthreads();
    s = reds[0] + reds[1] + reds[2] + reds[3];
    const float rs = 64.0f / s;
    half4 o4 = {(half_t)(e0 * rs), (half_t)(e1 * rs),
                (half_t)(e2 * rs), (half_t)(e3 * rs)};
    ((half4*)(Qh + (long)r * 1024))[t] = o4;
}

// ---------------------------------------------------------------------------
// row softmax over 4096 (sequence softmax in transposed [B,D,N] layout);
// one block per (b,d) row, 16 elems/thread. Output scaled by 64.
__global__ __launch_bounds__(256) void softmax_seq(
    const half_t* __restrict__ L, half_t* __restrict__ O)
{
    const long r = blockIdx.x;
    const int t = threadIdx.x;
    const half_t* row = L + r * 4096;
    const half8 h0 = *(const half8*)(row + t * 16);
    const half8 h1 = *(const half8*)(row + t * 16 + 8);
    float v[16];
#pragma unroll
    for (int j = 0; j < 8; j++) { v[j] = (float)h0[j]; v[8 + j] = (float)h1[j]; }
    float m = v[0];
#pragma unroll
    for (int j = 1; j < 16; j++) m = fmaxf(m, v[j]);
#pragma unroll
    for (int o = 32; o > 0; o >>= 1) m = fmaxf(m, __shfl_xor(m, o, 64));
    __shared__ float redm[4], reds[4];
    const int wave = t >> 6;
    if ((t & 63) == 0) redm[wave] = m;
    __syncthreads();
    m = fmaxf(fmaxf(redm[0], redm[1]), fmaxf(redm[2], redm[3]));
    float s = 0.0f;
#pragma unroll
    for (int j = 0; j < 16; j++) { v[j] = __expf(v[j] - m); s += v[j]; }
#pragma unroll
    for (int o = 32; o > 0; o >>= 1) s += __shfl_xor(s, o, 64);
    if ((t & 63) == 0) reds[wave] = s;
    __syncthreads();
    s = reds[0] + reds[1] + reds[2] + reds[3];
    const float rs = 64.0f / s;
    half8 o0, o1;
#pragma unroll
    for (int j = 0; j < 8; j++) {
        o0[j] = (half_t)(v[j] * rs);
        o1[j] = (half_t)(v[8 + j] * rs);
    }
    *(half8*)(O + r * 4096 + t * 16) = o0;
    *(half8*)(O + r * 4096 + t * 16 + 8) = o1;
}

// ---------------------------------------------------------------------------
extern "C" void kernel_launch(void* const* d_in, const int* in_sizes, int n_in,
                              void* d_out, int out_size, void* d_ws, size_t ws_size,
                              hipStream_t stream)
{
    const float* x  = (const float*)d_in[0];
    const float* Wq = (const float*)d_in[1];
    const float* Wk = (const float*)d_in[2];
    const float* Wv = (const float*)d_in[3];
    const float* Wo = (const float*)d_in[4];
    const float* bo = (const float*)d_in[5];
    float* out = (float*)d_out;

    // Region 0 (64 MiB): Xh (32, dead after V GEMM; then reused for the f16
    // split-K partials P) + L (32, f16 logits: Lq then Kt-logits).
    char* w = (char*)d_ws;
    half_t* Xh  = (half_t*)w;                           // 32 MiB (x as f16)
    half_t* P   = (half_t*)w;                           // 32 MiB (f16 split-K partials)
    half_t* L   = (half_t*)(w + ((size_t)R_ * D_ * 2)); // 32 MiB (f16 logits)
    w += (size_t)R_ * D_ * 4;
    half_t* Qh  = (half_t*)w; w += (size_t)R_ * D_ * 2;       // 32 MiB (q * 64)
    half_t* Kt  = (half_t*)w; w += (size_t)R_ * D_ * 2;       // 32 MiB [B,D,N] (k * 64)
    half_t* Vt  = (half_t*)w; w += (size_t)R_ * D_ * 2;       // 32 MiB [B,D,N]
    half_t* Wt  = (half_t*)w; w += (size_t)4 * D_ * D_ * 2;   // 8 MiB (Wq^T|Wk^T|Wv^T|Wo^T)
    half_t* ctx = (half_t*)w; w += (size_t)B_ * D_ * D_ * 2;  // 8 MiB (64 * K^T V)
    half_t* Mt  = (half_t*)w; w += (size_t)B_ * D_ * D_ * 2;  // 8 MiB (64 * (ctx Wo)^T)
    (void)ws_size; (void)in_sizes; (void)n_in; (void)out_size;

    const dim3 blk(256);
    const long M1 = 1L << 20;

    convert_f32_f16<<<R_ * D_ / (256 * 8), blk, 0, stream>>>(x, Xh);
    transpose_w4<<<dim3(32, 32, 4), dim3(32, 8), 0, stream>>>(Wq, Wk, Wv, Wo, Wt);

    // ---- Q: Lq[n,d] = Xh @ Wq^T^T (A big -> SWAP=1), then feature softmax
    gemm_bt<1, 0, 1><<<dim3(128, 8, 1), blk, 0, stream>>>(Xh, Wt, L, nullptr,
        1024, 1024, 1024, 1024, 0, 0, 0, 1.0f);
    softmax_rows<<<R_, blk, 0, stream>>>(L, Qh);

    // ---- K transposed: Ktlog[b][d][n] = sum_k Wk^T[d,k] Xh[b][n,k]
    // (B big -> SWAP=0). Sequence softmax is now a ROW softmax over 4096.
    gemm_bt<1, 0, 0><<<dim3(32, 8, B_), blk, 0, stream>>>(Wt + M1, Xh, L, nullptr,
        1024, 1024, 4096, 1024, 0, (long)N_ * D_, (long)D_ * N_, 1.0f);
    softmax_seq<<<B_ * D_, blk, 0, stream>>>(L, Kt);

    // ---- V transposed directly from GEMM: Vt[b][e][n]
    gemm_bt<1, 0, 0><<<dim3(32, 8, B_), blk, 0, stream>>>(Wt + 2 * M1, Xh, Vt, nullptr,
        1024, 1024, 4096, 1024, 0, (long)N_ * D_, (long)D_ * N_, 1.0f);

    // ---- ctx[b][d][e] = sum_n (64 k[n,d]) v[n,e], split-K=4, f16 partials
    // (Xh dead -> its region holds P)
    gemm_bt<1, 2, 1><<<dim3(8, 8, 16), blk, 0, stream>>>(Kt, Vt, P, nullptr,
        N_, N_, 1024, N_ / 4,
        (long)D_ * N_, (long)D_ * N_, M1, 1.0f);
    ctx_reduce_h<<<2048, blk, 0, stream>>>(P, ctx);

    // ---- Mt[b][e][d] = sum_f Wo[f][e] ctx[b][d][f], split-K=4 (A=Wo^T, Bt=ctx)
    gemm_bt<1, 2, 1><<<dim3(8, 8, 16), blk, 0, stream>>>(Wt + 3 * M1, ctx, P, nullptr,
        1024, 1024, 1024, 256,
        0, M1, M1, 1.0f);
    ctx_reduce_h<<<2048, blk, 0, stream>>>(P, Mt);

    // ---- out[b][n][e] = (sum_d 64 q[n,d] * Mt[b][e][d]) * 2^-25 + bo[e]
    // 2^-25 = (1/8 head scale) * (1/1024 D_OUT) * (1/64 q) * (1/64 k), all exact
    gemm_bt<2, 0, 1><<<dim3(32, 8, B_), blk, 0, stream>>>(Qh, Mt, out, bo,
        1024, 1024, 1024, 1024,
        (long)N_ * D_, M1, (long)N_ * D_,
        1.0f / 33554432.0f);
}